// Round 10
// baseline (116.213 us; speedup 1.0000x reference)
//
#include <hip/hip_runtime.h>

#define NPARC 289
#define NOUT  578
#define DIMK  512
#define BATCH 32768

typedef __bf16 bf16x8 __attribute__((ext_vector_type(8)));
typedef float floatx4 __attribute__((ext_vector_type(4)));

__device__ __forceinline__ unsigned short f2bf(float f) {
    unsigned u = __float_as_uint(f);
    u = (u + 0x7fffu + ((u >> 16) & 1u)) >> 16;
    return (unsigned short)u;
}

// prep (verified R5/R7/R9): INTERLEAVED col slots — slot 2j = re col j,
// slot 2j+1 = im col j (W row j+289); epilogue shares one sincos per pair.
// 16x16x32 A-operand order: m = ct*16 + (lane&15), k = ks*32 + (lane>>4)*8 + j.
__global__ void prep_w(const float* __restrict__ W, unsigned short* __restrict__ Wp) {
    int wid = threadIdx.x >> 6;
    int lane = threadIdx.x & 63;
    int slot = blockIdx.x * 4 + wid;         // [0, 640)
    int k = lane * 8;
    unsigned short v[8];
    if (slot < NOUT) {
        int o = (slot & 1) ? NPARC + (slot >> 1) : (slot >> 1);
        const float* src = W + (size_t)o * DIMK + k;
        #pragma unroll
        for (int j = 0; j < 8; ++j) v[j] = f2bf(src[j]);
    } else {
        #pragma unroll
        for (int j = 0; j < 8; ++j) v[j] = 0;
    }
    int ct = slot >> 4;
    int ks = k >> 5;
    int ln = (((k >> 3) & 3) << 4) + (slot & 15);
    uint4 o4;
    o4.x = (unsigned)v[0] | ((unsigned)v[1] << 16);
    o4.y = (unsigned)v[2] | ((unsigned)v[3] << 16);
    o4.z = (unsigned)v[4] | ((unsigned)v[5] << 16);
    o4.w = (unsigned)v[6] | ((unsigned)v[7] << 16);
    *(uint4*)(Wp + (size_t)((ct * 16 + ks) * 64 + ln) * 8) = o4;
}

// ROUND 16: R9 + intra-slab cluster PHASE ROTATION (single variable).
// Cross-round accounting: non-overlapped pipe sum (MFMA 8.0 + VALU 7.7 +
// VMEM-fill ~9 + DS ~6.6 + drains) == the measured 40us. All waves run the
// identical instruction sequence from common barriers, so co-resident waves
// always contend for the SAME pipe; the pipes serialize. Every single-pipe
// lever (occupancy 18-38%, W traffic 335-655MB, conflicts 0-1.3M, MFMA
// shape, async DMA, barrier flavor, prefetch depth) left time at 40-46us.
// Change: wave wid walks each slab's 4 clusters in order (rot..rot+3)&3,
// rot = ((wid&3)+((wid>>2)<<1))&3 — offsets {0,1,2,3,2,3,0,1}, distinct
// within a SIMD under either wave->SIMD mapping. Accumulation is order-
// invariant; all clusters are LDS-resident post-barrier; traffic, regs,
// LDS, barriers byte-identical to R9. Pure cross-wave pipe decorrelation.
__global__ __launch_bounds__(512, 2) void fused_kernel(
    const float* __restrict__ inputs, const float* __restrict__ targets,
    const float* __restrict__ bias, const unsigned short* __restrict__ Wp,
    float* __restrict__ out)
{
    __shared__ __align__(16) unsigned short buf[2][1024][8];  // 2 x 16 KiB bf16
    __shared__ float R[8][64][3];                             // 6 KiB
    const int tid  = threadIdx.x;
    const int base = blockIdx.x * 64;
    const int wid  = tid >> 6;
    const int lane = tid & 63;
    const int quad = lane >> 4;
    const int lcol = lane & 15;
    const int ct0  = wid * 5;
    const bf16x8* Wf = (const bf16x8*)Wp;

    // phase rotation: this wave's cluster-visit order within every slab
    const int rot = ((wid & 3) + ((wid >> 2) << 1)) & 3;
    const int c0 = rot;
    const int c1 = (rot + 1) & 3;
    const int c2 = (rot + 2) & 3;
    const int c3 = (rot + 3) & 3;

    // staging map: thread owns chunks (rowA, cch) and (rowB, cch); chunk =
    // 8 consecutive k (16 B bf16). phys chunk = cch ^ (row & 15).
    const int rowA  = tid >> 4;            // 0..31
    const int rowB  = 32 + (tid >> 4);     // 32..63
    const int cch   = tid & 15;
    const int physA = cch ^ (rowA & 15);
    const int physB = cch ^ (rowB & 15);
    const float* inb = inputs + (size_t)base * DIMK;

    float4 ga0, ga1, gb0, gb1;

#define GLOAD(t) do {                                                         \
    const float* pA_ = inb + (size_t)rowA * DIMK + (t) * 128 + cch * 8;       \
    const float* pB_ = inb + (size_t)rowB * DIMK + (t) * 128 + cch * 8;       \
    ga0 = *(const float4*)pA_; ga1 = *(const float4*)(pA_ + 4);               \
    gb0 = *(const float4*)pB_; gb1 = *(const float4*)(pB_ + 4);               \
} while (0)

#define CVTWRITE(nb) do {                                                     \
    union { __bf16 h[8]; uint4 u; } cA_, cB_;                                 \
    cA_.h[0]=(__bf16)ga0.x; cA_.h[1]=(__bf16)ga0.y;                           \
    cA_.h[2]=(__bf16)ga0.z; cA_.h[3]=(__bf16)ga0.w;                           \
    cA_.h[4]=(__bf16)ga1.x; cA_.h[5]=(__bf16)ga1.y;                           \
    cA_.h[6]=(__bf16)ga1.z; cA_.h[7]=(__bf16)ga1.w;                           \
    cB_.h[0]=(__bf16)gb0.x; cB_.h[1]=(__bf16)gb0.y;                           \
    cB_.h[2]=(__bf16)gb0.z; cB_.h[3]=(__bf16)gb0.w;                           \
    cB_.h[4]=(__bf16)gb1.x; cB_.h[5]=(__bf16)gb1.y;                           \
    cB_.h[6]=(__bf16)gb1.z; cB_.h[7]=(__bf16)gb1.w;                           \
    *(uint4*)&buf[nb][rowA * 16 + physA][0] = cA_.u;                          \
    *(uint4*)&buf[nb][rowB * 16 + physB][0] = cB_.u;                          \
} while (0)

#define LDAW(dst, ksg)                                                        \
    { _Pragma("unroll") for (int t5_ = 0; t5_ < 5; ++t5_)                     \
        dst[t5_] = Wf[((size_t)(ct0 + t5_) * 16 + (ksg)) * 64 + lane]; }

    // B fragment: sample st*16+lcol, k-chunk jl*4+quad (8 consecutive k)
#define LDBS(dst, nb, jl)                                                     \
    { _Pragma("unroll") for (int st_ = 0; st_ < 4; ++st_) {                   \
        int sr_ = st_ * 16 + lcol;                                            \
        dst[st_] = *(const bf16x8*)&buf[nb][sr_ * 16 +                        \
                       (((jl) * 4 + quad) ^ (sr_ & 15))][0]; }  }

#define MFMA20(AW, BS)                                                        \
    __builtin_amdgcn_sched_barrier(0);                                        \
    __builtin_amdgcn_s_setprio(1);                                            \
    { _Pragma("unroll") for (int t5_ = 0; t5_ < 5; ++t5_)                     \
      { _Pragma("unroll") for (int st_ = 0; st_ < 4; ++st_)                   \
          acc[t5_][st_] = __builtin_amdgcn_mfma_f32_16x16x32_bf16(            \
              AW[t5_], BS[st_], acc[t5_][st_], 0, 0, 0); } }                  \
    __builtin_amdgcn_s_setprio(0);                                            \
    __builtin_amdgcn_sched_barrier(0);

#define BARRIER_LGKM()                                                        \
    __builtin_amdgcn_sched_barrier(0);                                        \
    asm volatile("s_waitcnt lgkmcnt(0)" ::: "memory");                        \
    __builtin_amdgcn_sched_barrier(0);                                        \
    __builtin_amdgcn_s_barrier();                                             \
    __builtin_amdgcn_sched_barrier(0);

    floatx4 acc[5][4];
    #pragma unroll
    for (int t5 = 0; t5 < 5; ++t5)
        #pragma unroll
        for (int st = 0; st < 4; ++st) acc[t5][st] = (floatx4){0.f, 0.f, 0.f, 0.f};

    bf16x8 a0[5], a1[5], a2[5], bsA[4], bsB[4];

    // ---- prologue: stage slab 0, preload aw for first two rotated clusters
    LDAW(a0, c0);
    LDAW(a1, c1);
    GLOAD(0);
    CVTWRITE(0);                       // auto vmcnt wait on g (prologue only)
    __syncthreads();

    // ---- slab 0 (buf 0): consume a0,a1,a2,a0 ----
    GLOAD(1);
    LDBS(bsA, 0, c0);
    LDBS(bsB, 0, c1);  LDAW(a2, 0 + c2);   MFMA20(a0, bsA);
    LDBS(bsA, 0, c2);  LDAW(a0, 0 + c3);   MFMA20(a1, bsB);
    LDBS(bsB, 0, c3);  LDAW(a1, 4 + c0);   MFMA20(a2, bsA);
                       LDAW(a2, 4 + c1);   MFMA20(a0, bsB);
    CVTWRITE(1);
    BARRIER_LGKM();

    // ---- slab 1 (buf 1): consume a1,a2,a0,a1 ----
    GLOAD(2);
    LDBS(bsA, 1, c0);
    LDBS(bsB, 1, c1);  LDAW(a0, 4 + c2);   MFMA20(a1, bsA);
    LDBS(bsA, 1, c2);  LDAW(a1, 4 + c3);   MFMA20(a2, bsB);
    LDBS(bsB, 1, c3);  LDAW(a2, 8 + c0);   MFMA20(a0, bsA);
                       LDAW(a0, 8 + c1);   MFMA20(a1, bsB);
    CVTWRITE(0);
    BARRIER_LGKM();

    // ---- slab 2 (buf 0): consume a2,a0,a1,a2 ----
    GLOAD(3);
    LDBS(bsA, 0, c0);
    LDBS(bsB, 0, c1);  LDAW(a1, 8 + c2);   MFMA20(a2, bsA);
    LDBS(bsA, 0, c2);  LDAW(a2, 8 + c3);   MFMA20(a0, bsB);
    LDBS(bsB, 0, c3);  LDAW(a0, 12 + c0);  MFMA20(a1, bsA);
                       LDAW(a1, 12 + c1);  MFMA20(a2, bsB);
    CVTWRITE(1);
    BARRIER_LGKM();

    // ---- slab 3 (buf 1): consume a0,a1,a2,a0 ----
    LDBS(bsA, 1, c0);
    LDBS(bsB, 1, c1);  LDAW(a2, 12 + c2);  MFMA20(a0, bsA);
    LDBS(bsA, 1, c2);  LDAW(a0, 12 + c3);  MFMA20(a1, bsB);
    LDBS(bsB, 1, c3);                      MFMA20(a2, bsA);
                                           MFMA20(a0, bsB);

    // ---- epilogue: paired re/im cols share one sincos (revolutions) ----
    float xs[4], ys[4];
    #pragma unroll
    for (int st = 0; st < 4; ++st) {
        float2 t2 = *(const float2*)(targets + 2 * (base + st * 16 + lcol));
        xs[st] = 0.5f * t2.x;             // sin(pi*z) = v_sin(z/2 rev)
        ys[st] = 0.5f * t2.y;
    }

    float pd[4]  = {0.f, 0.f, 0.f, 0.f};
    float pr[4]  = {0.f, 0.f, 0.f, 0.f};
    float pim[4] = {0.f, 0.f, 0.f, 0.f};

    #pragma unroll
    for (int t5 = 0; t5 < 5; ++t5)
        #pragma unroll
        for (int p = 0; p < 2; ++p) {
            int colw = (ct0 + t5) * 16 + quad * 4 + 2 * p;   // even slot
            if (colw < NOUT) {
                int jj = colw >> 1;
                int r = jj / 17;
                int c = jj - r * 17;
                float cf = (float)c, rf = (float)r;
                float be = bias[jj];
                float bo = bias[jj + NPARC];
                #pragma unroll
                for (int st = 0; st < 4; ++st) {
                    float ve = acc[t5][st][2 * p]     + be;
                    float vo = acc[t5][st][2 * p + 1] + bo;
                    float u = fmaf(cf, xs[st], rf * ys[st]);
                    u = __builtin_amdgcn_fractf(u);
                    float sn = __builtin_amdgcn_sinf(u);
                    float cs = __builtin_amdgcn_cosf(u);
                    pd[st]  = fmaf(ve, ve, pd[st]);
                    pd[st]  = fmaf(vo, vo, pd[st]);
                    pr[st]  = fmaf(ve, cs, pr[st]);
                    pr[st]  = fmaf(-vo, sn, pr[st]);
                    pim[st] = fmaf(ve, sn, pim[st]);
                    pim[st] = fmaf(vo, cs, pim[st]);
                }
            }
        }

    // fold the 4 quads (weight-col rows) — butterfly on lane bits 4,5
    #pragma unroll
    for (int d = 16; d < 64; d <<= 1)
        #pragma unroll
        for (int st = 0; st < 4; ++st) {
            pd[st]  += __shfl_xor(pd[st], d, 64);
            pr[st]  += __shfl_xor(pr[st], d, 64);
            pim[st] += __shfl_xor(pim[st], d, 64);
        }

    if (lane < 16) {
        #pragma unroll
        for (int st = 0; st < 4; ++st) {
            int sl = st * 16 + lane;
            R[wid][sl][0] = pd[st];
            R[wid][sl][1] = pr[st];
            R[wid][sl][2] = pim[st];
        }
    }
    __syncthreads();

    if (tid < 64) {
        float sd = 0.f, sr = 0.f, si = 0.f;
        #pragma unroll
        for (int w = 0; w < 8; ++w) {
            sd += R[w][tid][0];
            sr += R[w][tid][1];
            si += R[w][tid][2];
        }
        out[base + tid] = (sr * sr + si * si) / (4.0f * sd);
    }
#undef GLOAD
#undef CVTWRITE
#undef LDAW
#undef LDBS
#undef MFMA20
#undef BARRIER_LGKM
}

extern "C" void kernel_launch(void* const* d_in, const int* in_sizes, int n_in,
                              void* d_out, int out_size, void* d_ws, size_t ws_size,
                              hipStream_t stream) {
    const float* inputs  = (const float*)d_in[0];
    const float* targets = (const float*)d_in[1];
    const float* W       = (const float*)d_in[2];
    const float* bias    = (const float*)d_in[3];
    unsigned short* Wp   = (unsigned short*)d_ws;   // 640 KiB of ws

    prep_w<<<160, 256, 0, stream>>>(W, Wp);
    fused_kernel<<<BATCH / 64, 512, 0, stream>>>(inputs, targets, bias, Wp, (float*)d_out);
}